// Round 12
// baseline (226.319 us; speedup 1.0000x reference)
//
#include <hip/hip_runtime.h>
#include <stdint.h>

#define BDIM 4
#define TDIM 4096
#define CDIM 1024
#define MDIM (BDIM * TDIM) // 16384
#define SSEG 64            // segments along T
#define LSEG 64            // steps per segment
#define NCH  (BDIM * CDIM) // 4096 channels

#define GK   1024          // GEMM K
#define GK2  2048          // K row stride in bytes (bf16)
#define NT32 32            // K-tiles of 32

typedef __attribute__((ext_vector_type(8))) short bf16x8;
typedef __attribute__((ext_vector_type(4))) float f32x4;

__device__ __forceinline__ unsigned short f2bf(float f) {
    unsigned u = __builtin_bit_cast(unsigned, f);
    u = u + 0x7fffu + ((u >> 16) & 1u); // RNE
    return (unsigned short)(u >> 16);
}
__device__ __forceinline__ float bf2f(unsigned short h) {
    unsigned u = ((unsigned)h) << 16;
    return __builtin_bit_cast(float, u);
}

typedef __attribute__((address_space(1))) const unsigned int g_u32;
typedef __attribute__((address_space(3))) unsigned int l_u32;
__device__ __forceinline__ void gload_lds16(const void* g, void* l) {
    __builtin_amdgcn_global_load_lds((g_u32*)g, (l_u32*)l, 16, 0, 0);
}

// ---------------- all fp32 -> bf16 casts in ONE launch ----------------
__global__ void castall(const float* __restrict__ x,
                        const float* __restrict__ kw, const float* __restrict__ vw,
                        const float* __restrict__ rw, const float* __restrict__ ow,
                        unsigned short* __restrict__ xb,
                        unsigned short* __restrict__ wf, unsigned short* __restrict__ owb) {
    int i = blockIdx.x * 256 + threadIdx.x;
    const float* s;
    unsigned short* d;
    int j;
    if (i < 4194304) {                       // x
        s = x; d = xb; j = i;
    } else {
        int k = i - 4194304;
        int m = k >> 18; j = k & 262143;     // which weight
        s = (m == 0) ? kw : (m == 1) ? vw : (m == 2) ? rw : ow;
        d = (m < 3) ? (wf + (size_t)m * 1048576) : owb;
    }
    float4 f = ((const float4*)s)[j];
    ushort4 o;
    o.x = f2bf(f.x); o.y = f2bf(f.y); o.z = f2bf(f.z); o.w = f2bf(f.w);
    ((ushort4*)d)[j] = o;
}

// ---------------- 256x256 bf16 GEMM, BK=32, 4-slot LDS ring -----------------
// 512 threads = 8 waves (2M x 4N), 16x16x32 MFMA (1 k-step per BK-32 tile).
// 32 K-tiles, 2 phases each, 4-slot ring -> prefetch depth 3 K-tiles
// (6 loads in flight, ONE vmcnt(6) per tile at P0-end), fine interleave
// (4-8 ds_read + 16 MFMA per phase). LDS tile stored as 128 lines x 128B
// (2 rows/line) with the proven XOR swizzle byte^=((line&7)<<4) both-sides.
//  P0(t): read a47(t); stage A(t+3); bar; MFMA a03(t) x b(t); vmcnt; bar
//  P1(t): read a03(t+1)+b(t+1) (slot t+1); stage B(t+3); bar; MFMA a47 x b; bar
// Ledger: vmcnt(6)@P0(t) lands exactly through B(t+1) (issue order
// A0B0A1B1A2B2 then A3B3A4B4...); slot overwrites >= 2 barriers after last
// read. b ping-pong via 2x loop unroll (compile-time). Tail vmcnt: 4@29,0@30.
// MODE 0: fused QKV epilogue -> oK/oV(bf16), oR(sigmoid,bf16). MODE 1: fp32.

#define MFMA16(ACCROW, AREG, BREG)                                          \
    _Pragma("unroll") for (int a_ = 0; a_ < 4; ++a_)                        \
    _Pragma("unroll") for (int b_ = 0; b_ < 4; ++b_)                        \
        acc[ACCROW + a_][b_] = __builtin_amdgcn_mfma_f32_16x16x32_bf16(     \
            AREG[a_], BREG[b_], acc[ACCROW + a_][b_], 0, 0, 0);

#define KT32(T, BU, BN)                                                     \
  {                                                                         \
    const int slot  = (T) & 3;                                              \
    const int slotN = ((T) + 1) & 3;                                        \
    /* P0: read a47(t); stage A(t+3); MFMA a03 x BU */                      \
    {                                                                       \
        const char* ab = shA + slot * 16384 + wm * 8192 + aoffc;            \
        _Pragma("unroll") for (int m_ = 0; m_ < 4; ++m_)                    \
            a47[m_] = *(const bf16x8*)(ab + (4 + m_) * 1024);               \
    }                                                                       \
    stage((T) + 3, 0);                                                      \
    __builtin_amdgcn_s_barrier();                                           \
    __builtin_amdgcn_s_setprio(1);                                          \
    MFMA16(0, a03, BU)                                                      \
    __builtin_amdgcn_s_setprio(0);                                          \
    if ((T) <= 28)      asm volatile("s_waitcnt vmcnt(6)" ::: "memory");    \
    else if ((T) == 29) asm volatile("s_waitcnt vmcnt(4)" ::: "memory");    \
    else if ((T) == 30) asm volatile("s_waitcnt vmcnt(0)" ::: "memory");    \
    __builtin_amdgcn_s_barrier();                                           \
    /* P1: read a03(t+1)+BN(t+1); stage B(t+3); MFMA a47 x BU */            \
    if ((T) + 1 < NT32) {                                                   \
        const char* abN = shA + slotN * 16384 + wm * 8192 + aoffc;          \
        const char* bbN = shB + slotN * 16384 + wn * 4096 + aoffc;          \
        _Pragma("unroll") for (int m_ = 0; m_ < 4; ++m_)                    \
            a03[m_] = *(const bf16x8*)(abN + m_ * 1024);                    \
        _Pragma("unroll") for (int n_ = 0; n_ < 4; ++n_)                    \
            BN[n_] = *(const bf16x8*)(bbN + n_ * 1024);                     \
    }                                                                       \
    stage((T) + 3, 1);                                                      \
    __builtin_amdgcn_s_barrier();                                           \
    __builtin_amdgcn_s_setprio(1);                                          \
    MFMA16(4, a47, BU)                                                      \
    __builtin_amdgcn_s_setprio(0);                                          \
    __builtin_amdgcn_s_barrier();                                           \
  }

template <int MODE, int NT>
__global__ __launch_bounds__(512, 2) void gemm256(
    const unsigned short* __restrict__ A,
    const unsigned short* __restrict__ Bw,
    unsigned short* __restrict__ oK, unsigned short* __restrict__ oV,
    unsigned short* __restrict__ oR, float* __restrict__ oF)
{
    extern __shared__ char sh[];
    char* shA = sh;             // 4 slots x 16384 B (256 rows x 32 cols bf16)
    char* shB = sh + 65536;     // 4 slots x 16384 B

    const int tid  = threadIdx.x;
    const int wave = tid >> 6;
    const int lane = tid & 63;
    const int wm   = wave >> 2;      // 0..1 (M half)
    const int wn   = wave & 3;       // 0..3 (N quarter)
    const int lrow = lane & 15;
    const int koct = lane >> 4;      // 0..3

    // LDS layout: line L (128B) holds rows 2L,2L+1 (64B each) of the tile.
    // read byte for row r, k-octet koct:
    //   (r>>1)*128 + (((r&1)*64 + koct*16) ^ (((r>>1)&7)<<4))
    // per-thread constant part (mi*16 doesn't touch (r>>1)&7):
    const int aoffc = (lrow >> 1) * 128 +
                      ((((lrow & 1) * 64) + koct * 16) ^ (((lrow >> 1) & 7) << 4));

    // stage source pre-swizzle (chunk d=tid*16 and d+8192):
    const int inl  = ((tid & 7) * 16) ^ (((tid >> 3) & 7) << 4);
    const int sg0r = 2 * (tid >> 3) + (inl >> 6);   // global row of chunk 0
    const int sgc  = inl & 63;                      // byte within 64B row-seg
    const int sd0  = tid * 16;
    const int sd1  = 8192 + tid * 16;

    // L2-locality XCD swizzle (grid = 8 * 8 * NT blocks)
    const int bid = blockIdx.x;
    const int xcd = bid & 7;
    const int idx = bid >> 3;
    const int mt  = xcd * 8 + idx / NT;  // disjoint A-slice per XCD
    const int nt  = idx % NT;            // nt-fast: A panel L2-reused
    const size_t row0 = (size_t)mt * 256;
    const size_t col0 = (size_t)nt * 256;

    const char* gA = (const char*)A  + row0 * GK2;
    const char* gB = (const char*)Bw + col0 * GK2;

    // stage whole 256x32 tile tt of A (isB=0) or B (isB=1): 2 gloads/thread
    auto stage = [&](int tt, int isB) {
        if (tt >= NT32) return;
        int slot = tt & 3;
        const char* gbase = (isB ? gB : gA) + tt * 64;
        char* lbase = (isB ? shB : shA) + slot * 16384;
        gload_lds16(gbase + (size_t)sg0r * GK2 + sgc, lbase + sd0);
        gload_lds16(gbase + (size_t)(sg0r + 128) * GK2 + sgc, lbase + sd1);
    };

    // prologue: tiles 0,1,2 (A,B each) = 12 loads; wait tile0 (8 outstanding)
    stage(0, 0); stage(0, 1);
    stage(1, 0); stage(1, 1);
    stage(2, 0); stage(2, 1);
    asm volatile("s_waitcnt vmcnt(8)" ::: "memory");
    __builtin_amdgcn_s_barrier();

    f32x4 acc[8][4] = {};
    bf16x8 a03[4], a47[4], bA[4], bB[4];

    // pre-read a03(0), bA(0) from slot 0
    {
        const char* ab0 = shA + wm * 8192 + aoffc;
        const char* bb0 = shB + wn * 4096 + aoffc;
#pragma unroll
        for (int m = 0; m < 4; ++m) a03[m] = *(const bf16x8*)(ab0 + m * 1024);
#pragma unroll
        for (int n = 0; n < 4; ++n) bA[n] = *(const bf16x8*)(bb0 + n * 1024);
    }

    for (int tt = 0; tt < NT32; tt += 2) {
        KT32(tt,     bA, bB)
        KT32(tt + 1, bB, bA)
    }

    // ---- epilogue: C/D frag layout col=lane&15, row=(lane>>4)*4+j
    const int crow = (lane >> 4) * 4;
    const int ccol = lane & 15;
    if (MODE == 1) {
#pragma unroll
        for (int mi = 0; mi < 8; ++mi)
#pragma unroll
            for (int ni = 0; ni < 4; ++ni) {
                size_t gr = row0 + wm * 128 + mi * 16 + crow;
                size_t gc = col0 + wn * 64 + ni * 16 + ccol;
#pragma unroll
                for (int j = 0; j < 4; ++j)
                    oF[(gr + j) * 1024 + gc] = acc[mi][ni][j];
            }
    } else {
        const int region = nt >> 2;  // 0=K, 1=V, 2=R
        unsigned short* dst = (region == 0) ? oK : ((region == 1) ? oV : oR);
        const size_t cb0 = (size_t)(nt & 3) * 256;
#pragma unroll
        for (int mi = 0; mi < 8; ++mi)
#pragma unroll
            for (int ni = 0; ni < 4; ++ni) {
                size_t gr = row0 + wm * 128 + mi * 16 + crow;
                size_t gc = cb0 + wn * 64 + ni * 16 + ccol;
#pragma unroll
                for (int j = 0; j < 4; ++j) {
                    float val = acc[mi][ni][j];
                    if (region == 2) val = 1.0f / (1.0f + __expf(-val));
                    dst[(gr + j) * 1024 + gc] = f2bf(val);
                }
            }
    }
}

// ---------------- WKV segmented scan (bf16 k,v,r) ----------------
__global__ __launch_bounds__(256) void wkv_phase1(
    const unsigned short* __restrict__ kf, const unsigned short* __restrict__ vf,
    const float* __restrict__ td,
    float* __restrict__ segA, float* __restrict__ segB, float* __restrict__ segP)
{
    const int tid  = blockIdx.x * 256 + threadIdx.x;
    const int lane = tid & 63;
    const int wg   = tid >> 6;
    const int cg   = wg & 63;
    const int s    = wg >> 6;
    const int q    = cg * 64 + lane;
    const int b    = q >> 10;
    const int c    = q & (CDIM - 1);

    const float w = __expf(td[c]);

    float aa = 0.0f, bb = 0.0f, pp = -1e38f;
    size_t idx = (size_t)b * TDIM * CDIM + (size_t)(s * LSEG) * CDIM + c;
#pragma unroll 4
    for (int i = 0; i < LSEG; ++i, idx += CDIM) {
        float kt = bf2f(kf[idx]);
        float vt = bf2f(vf[idx]);
        float ww2 = pp - w;
        float p2  = fmaxf(ww2, kt);
        float e1  = __expf(ww2 - p2);
        float e2  = __expf(kt - p2);
        aa = e1 * aa + e2 * vt;
        bb = e1 * bb + e2;
        pp = p2;
    }
    segA[s * NCH + q] = aa;
    segB[s * NCH + q] = bb;
    segP[s * NCH + q] = pp;
}

__global__ __launch_bounds__(256) void wkv_phase2(
    const float* __restrict__ segA, const float* __restrict__ segB, const float* __restrict__ segP,
    const float* __restrict__ td,
    const float* __restrict__ aa0, const float* __restrict__ bb0, const float* __restrict__ pp0,
    float* __restrict__ preA, float* __restrict__ preB, float* __restrict__ preP,
    float* __restrict__ stout)
{
    const int tid = blockIdx.x * 256 + threadIdx.x;   // 0..NCH-1
    const int c = tid & (CDIM - 1);
    const float w  = __expf(td[c]);
    const float Lw = (float)LSEG * w;

    float aa = aa0[tid], bb = bb0[tid], pp = pp0[tid];
    for (int s = 0; s < SSEG; ++s) {
        preA[s * NCH + tid] = aa;
        preB[s * NCH + tid] = bb;
        preP[s * NCH + tid] = pp;
        float al = segA[s * NCH + tid];
        float bl = segB[s * NCH + tid];
        float pl = segP[s * NCH + tid];
        float ppd = pp - Lw;
        float p  = fmaxf(ppd, pl);
        float e1 = __expf(ppd - p);
        float e2 = __expf(pl - p);
        aa = e1 * aa + e2 * al;
        bb = e1 * bb + e2 * bl;
        pp = p;
    }
    stout[tid]           = aa;
    stout[NCH + tid]     = bb;
    stout[2 * NCH + tid] = pp;
}

__global__ __launch_bounds__(256) void wkv_phase3(
    const unsigned short* __restrict__ kf, const unsigned short* __restrict__ vf,
    const unsigned short* __restrict__ rb,
    const float* __restrict__ td, const float* __restrict__ tf,
    const float* __restrict__ preA, const float* __restrict__ preB, const float* __restrict__ preP,
    unsigned short* __restrict__ rwkvb)
{
    const int tid  = blockIdx.x * 256 + threadIdx.x;
    const int lane = tid & 63;
    const int wg   = tid >> 6;
    const int cg   = wg & 63;
    const int s    = wg >> 6;
    const int q    = cg * 64 + lane;
    const int b    = q >> 10;
    const int c    = q & (CDIM - 1);

    const float w = __expf(td[c]);
    const float u = tf[c];

    float aa = preA[s * NCH + q];
    float bb = preB[s * NCH + q];
    float pp = preP[s * NCH + q];

    size_t idx = (size_t)b * TDIM * CDIM + (size_t)(s * LSEG) * CDIM + c;
#pragma unroll 4
    for (int i = 0; i < LSEG; ++i, idx += CDIM) {
        float kt = bf2f(kf[idx]);
        float vt = bf2f(vf[idx]);
        float rt = bf2f(rb[idx]);
        float ww = u + kt;
        float p  = fmaxf(pp, ww);
        float e1 = __expf(pp - p);
        float e2 = __expf(ww - p);
        float wkv = (e1 * aa + e2 * vt) / (e1 * bb + e2);
        rwkvb[idx] = f2bf(rt * wkv);
        float ww2 = pp - w;
        float p2  = fmaxf(ww2, kt);
        float e1b = __expf(ww2 - p2);
        float e2b = __expf(kt - p2);
        aa = e1b * aa + e2b * vt;
        bb = e1b * bb + e2b;
        pp = p2;
    }
}

extern "C" void kernel_launch(void* const* d_in, const int* in_sizes, int n_in,
                              void* d_out, int out_size, void* d_ws, size_t ws_size,
                              hipStream_t stream) {
    const float* x   = (const float*)d_in[0];
    const float* kw  = (const float*)d_in[1];
    const float* vw  = (const float*)d_in[2];
    const float* rw  = (const float*)d_in[3];
    const float* ow  = (const float*)d_in[4];
    const float* td  = (const float*)d_in[5];
    const float* tf  = (const float*)d_in[6];
    const float* aa0 = (const float*)d_in[7];
    const float* bb0 = (const float*)d_in[8];
    const float* pp0 = (const float*)d_in[9];
    float* out = (float*)d_out;

    char* ws = (char*)d_ws;
    unsigned short* wf    = (unsigned short*)(ws);               //  6,291,456 B  [3072][1024] bf16
    unsigned short* owb   = (unsigned short*)(ws + 6291456);     //  2,097,152 B
    unsigned short* xb    = (unsigned short*)(ws + 8388608);     // 33,554,432 B
    unsigned short* kfb   = (unsigned short*)(ws + 41943040);    // 33,554,432 B
    unsigned short* vfb   = (unsigned short*)(ws + 75497472);    // 33,554,432 B
    unsigned short* rbb   = (unsigned short*)(ws + 109051904);   // 33,554,432 B
    unsigned short* rwkvb = (unsigned short*)(ws + 142606336);   // 33,554,432 B
    float* segA = (float*)(ws + 176160768);
    float* segB = (float*)(ws + 177209344);
    float* segP = (float*)(ws + 178257920);
    float* preA = (float*)(ws + 179306496);
    float* preB = (float*)(ws + 180355072);
    float* preP = (float*)(ws + 181403648);

    hipFuncSetAttribute((const void*)(gemm256<0, 12>), hipFuncAttributeMaxDynamicSharedMemorySize, 131072);
    hipFuncSetAttribute((const void*)(gemm256<1, 4>),  hipFuncAttributeMaxDynamicSharedMemorySize, 131072);

    // all casts in one launch
    castall<<<20480, 256, 0, stream>>>(x, kw, vw, rw, ow, xb, wf, owb);

    // fused QKV projection: [16384,1024] x [3072,1024]^T, 768 blocks
    gemm256<0, 12><<<768, 512, 131072, stream>>>(xb, wf, kfb, vfb, rbb, nullptr);

    // segmented WKV scan
    wkv_phase1<<<NCH * SSEG / 256, 256, 0, stream>>>(kfb, vfb, td, segA, segB, segP);
    wkv_phase2<<<NCH / 256, 256, 0, stream>>>(segA, segB, segP, td, aa0, bb0, pp0,
                                              preA, preB, preP, out + (size_t)MDIM * CDIM);
    wkv_phase3<<<NCH * SSEG / 256, 256, 0, stream>>>(kfb, vfb, rbb, td, tf,
                                                     preA, preB, preP, rwkvb);

    // output projection: [16384,1024] x [1024,1024]^T -> fp32 d_out, 256 blocks
    gemm256<1, 4><<<256, 512, 131072, stream>>>(rwkvb, owb, nullptr, nullptr, nullptr, out);
}